// Round 9
// baseline (148.927 us; speedup 1.0000x reference)
//
#include <hip/hip_runtime.h>

#define T_LEN 32768
#define TT 64
#define SWZ(row) ((((row) >> 1) & 7) << 4)

// LDS layout (bytes): xs 80*128, csA 64*128, csB 64*32
#define XS_OFF   0
#define CSA_OFF  10240
#define CSB_OFF  18432
#define LDS_SZ   20480   // x8 blocks/CU = 160 KiB exactly

typedef unsigned short ushort;
typedef unsigned int uint;
typedef __attribute__((ext_vector_type(8))) short short8;   // 8 bf16
typedef __attribute__((ext_vector_type(4))) float f32x4;
typedef __attribute__((ext_vector_type(2))) uint uint2v;

// Fragment-packed bf16 weights (one linear blob, L2-resident, read by all blocks).
// ushort layout: [0,32768) A1 full k-steps; [32768,34816) A8 half-frags; [34816,38912) A2.
__device__ __align__(16) ushort g_packAll[38912];

static __device__ __forceinline__ ushort f2bf(float f) {    // RNE f32->bf16
    uint u = __float_as_uint(f);
    u += 0x7fffu + ((u >> 16) & 1u);
    return (ushort)(u >> 16);
}

// A-frag (16x16x32): lane l holds A[16m + (l&15)][32s + (l>>4)*8 + j]
__global__ void pack_weights(const float* __restrict__ wconv,
                             const float* __restrict__ wcond,
                             const float* __restrict__ wout) {
    int idx = blockIdx.x * 256 + threadIdx.x;
    if (idx >= 38912) return;
    float v;
    if (idx < 32768) {                   // A1 full k-steps s=0..7 (conv 6 + cond 2)
        int j = idx & 7, lane = (idx >> 3) & 63, f = idx >> 9;  // f = s*8+g
        int s = f >> 3, g = f & 7;
        int row = (g & 3) * 16 + (lane & 15) + ((g & 4) ? 64 : 0);
        int k = s * 32 + (lane >> 4) * 8 + j;
        if (k < 192) v = wconv[row * 192 + (k & 63) * 3 + (k >> 6)];  // tap-major k
        else         v = wcond[row * 80 + (k - 192)];
    } else if (idx < 34816) {            // s=8 half-frags: k = cc 64..79 (l4<2 lanes)
        int e = idx - 32768;
        int j = e & 7, lane32 = (e >> 3) & 31, g = e >> 8;
        int row = (g & 3) * 16 + (lane32 & 15) + ((g & 4) ? 64 : 0);
        v = wcond[row * 80 + 64 + (lane32 >> 4) * 8 + j];
    } else {                             // A2: wout, f2 = s2*4 + m
        int e = idx - 34816;
        int j = e & 7, lane = (e >> 3) & 63, f2 = e >> 9;
        int row = (f2 & 3) * 16 + (lane & 15);
        v = wout[row * 64 + (f2 >> 2) * 32 + (lane >> 4) * 8 + j];
    }
    g_packAll[idx] = f2bf(v);
}

// 4096 blocks x 256 threads (4 waves = 2mw x 2nw), one 64-t tile each.
// __launch_bounds__(256, 8): min 8 waves/EU -> VGPR cap 64, occupancy cap lifted
// (R8's waves_per_eu(4,4) max-capped residency at 16 waves/CU; LDS 20480 allows
// 8 blocks/CU = 32 waves/CU = full occupancy for latency hiding).
__global__ __launch_bounds__(256, 8) void wavenet_mfma(
    const float* __restrict__ x, const float* __restrict__ cond,
    const float* __restrict__ bconv, const float* __restrict__ bout,
    float* __restrict__ out, float* __restrict__ skip)
{
    __shared__ __align__(16) char lds[LDS_SZ];
    const int tid = threadIdx.x;
    // XCD-aware swizzle: 512 consecutive t-tiles per XCD (bijective, 4096 % 8 == 0)
    const int bid = ((blockIdx.x & 7) << 9) | (blockIdx.x >> 3);
    const int b   = bid >> 9;
    const int t0  = (bid & 511) * TT;

    // ---- staging items: 0..159 x(oct,tq), 160..287 csA, 288..319 csB ----
    auto item_load = [&](int i, f32x4* v) {
        const float* p;
        bool ok = true;
        if (i < 160) {
            int oct = i & 7, tq = i >> 3;
            int g0 = t0 - 16 + tq * 4;
            ok = (g0 >= 0);
            p = x + (size_t)(b * 64 + oct * 8) * T_LEN + g0;
        } else if (i < 288) {
            int e = i - 160; int oct = e & 7, tq = e >> 3;
            p = cond + (size_t)(b * 80 + oct * 8) * T_LEN + t0 + tq * 4;
        } else {
            int e = i - 288; int octl = e & 1, tq = e >> 1;
            p = cond + (size_t)(b * 80 + 64 + octl * 8) * T_LEN + t0 + tq * 4;
        }
        if (ok) {
            #pragma unroll
            for (int j = 0; j < 8; ++j) v[j] = *(const f32x4*)(p + (size_t)j * T_LEN);
        } else {
            #pragma unroll
            for (int j = 0; j < 8; ++j) v[j] = (f32x4){0.f, 0.f, 0.f, 0.f};
        }
    };
    auto item_write = [&](int i, const f32x4* v) {
        char* basep; int tl, chunk; bool isB = false;
        if (i < 160)      { basep = lds + XS_OFF;  tl = (i >> 3) * 4;               chunk = (i & 7) * 16; }
        else if (i < 288) { int e = i - 160; basep = lds + CSA_OFF; tl = (e >> 3) * 4; chunk = (e & 7) * 16; }
        else              { int e = i - 288; basep = lds + CSB_OFF; tl = (e >> 1) * 4; chunk = (e & 1) * 16; isB = true; }
        #pragma unroll
        for (int r = 0; r < 4; ++r) {
            short8 pk;
            #pragma unroll
            for (int j = 0; j < 8; ++j) pk[j] = (short)f2bf(v[j][r]);
            int row = tl + r;
            int byte = isB ? row * 32 + (chunk ^ (((row >> 2) & 1) << 4))
                           : row * 128 + (chunk ^ SWZ(row));
            *(short8*)(basep + byte) = pk;
        }
    };

    // coverage: items [0,320), stride-256 loop (tid<64 serially takes a second item)
    for (int i = tid; i < 320; i += 256) {
        f32x4 va[8];
        item_load(i, va);
        item_write(i, va);
    }
    __syncthreads();

    const int lane = tid & 63, wv = tid >> 6;
    const int mw = wv & 1, nw = wv >> 1;          // 2 x 2 over 128 rows x 64 t
    const int l4 = lane >> 4, l15 = lane & 15;
    const short8* pW = (const short8*)g_packAll;  // A1 at frag 0, A8 at 4096, A2 at 4352

    // ---- phase A: y = conv(*)x + Wcond*c + bconv ----
    f32x4 accA[2][2], accG[2][2];
    #pragma unroll
    for (int i = 0; i < 2; ++i) {
        int rb = mw * 32 + i * 16 + l4 * 4;
        f32x4 ba = *(const f32x4*)(bconv + rb);
        f32x4 bg = *(const f32x4*)(bconv + 64 + rb);
        #pragma unroll
        for (int ni = 0; ni < 2; ++ni) { accA[i][ni] = ba; accG[i][ni] = bg; }
    }

    #pragma unroll
    for (int s = 0; s < 9; ++s) {
        short8 B[2];
        #pragma unroll
        for (int ni = 0; ni < 2; ++ni) {
            int col = nw * 32 + ni * 16 + l15;
            if (s < 6) {            // conv tap s>>1, c-half s&1; tap shifts t by 8*tap
                int tl = col + (s >> 1) * 8;
                B[ni] = *(const short8*)(lds + XS_OFF + tl * 128 + (((s & 1) * 64 + l4 * 16) ^ SWZ(tl)));
            } else if (s < 8) {     // cond cc (s-6)*32..+32
                B[ni] = *(const short8*)(lds + CSA_OFF + col * 128 + (((s - 6) * 64 + l4 * 16) ^ SWZ(col)));
            } else {                // cond cc 64..79 (half-K; l4>=2 lanes get zero A)
                B[ni] = *(const short8*)(lds + CSB_OFF + col * 32 + (((l4 & 1) * 16) ^ (((col >> 2) & 1) << 4)));
            }
        }
        #pragma unroll
        for (int i = 0; i < 2; ++i) {
            short8 Aa, Ag;
            if (s < 8) {
                Aa = pW[(s * 8 + mw * 2 + i) * 64 + lane];
                Ag = pW[(s * 8 + 4 + mw * 2 + i) * 64 + lane];
            } else if (l4 < 2) {
                Aa = pW[4096 + (mw * 2 + i) * 32 + lane];
                Ag = pW[4096 + (4 + mw * 2 + i) * 32 + lane];
            } else {
                Aa = (short8){0,0,0,0,0,0,0,0};
                Ag = (short8){0,0,0,0,0,0,0,0};
            }
            #pragma unroll
            for (int ni = 0; ni < 2; ++ni) {
                accA[i][ni] = __builtin_amdgcn_mfma_f32_16x16x32_bf16(Aa, B[ni], accA[i][ni], 0, 0, 0);
                accG[i][ni] = __builtin_amdgcn_mfma_f32_16x16x32_bf16(Ag, B[ni], accG[i][ni], 0, 0, 0);
            }
        }
    }
    __syncthreads();   // xs reads done -> zs may overlay

    // ---- gate (register-only) + skip store + z -> LDS ----
    char* zs = lds + XS_OFF;    // [64 t][64 r] bf16, 128B rows, SWZ on t
    #pragma unroll
    for (int i = 0; i < 2; ++i) {
        int rb = mw * 32 + i * 16 + l4 * 4;
        #pragma unroll
        for (int ni = 0; ni < 2; ++ni) {
            int col = nw * 32 + ni * 16 + l15;
            float z[4];
            #pragma unroll
            for (int j = 0; j < 4; ++j) {
                float a = accA[i][ni][j], g = accG[i][ni][j];
                float th = 1.f - 2.f * __builtin_amdgcn_rcpf(__expf(2.f * a) + 1.f);
                float sg = __builtin_amdgcn_rcpf(1.f + __expf(-g));
                z[j] = th * sg;
                skip[(size_t)(b * 64 + rb + j) * T_LEN + t0 + col] = z[j];
            }
            uint p0 = (uint)f2bf(z[0]) | ((uint)f2bf(z[1]) << 16);
            uint p1 = (uint)f2bf(z[2]) | ((uint)f2bf(z[3]) << 16);
            *(uint2v*)(zs + col * 128 + ((uint)(rb * 2) ^ SWZ(col))) = (uint2v){p0, p1};
        }
    }
    __syncthreads();

    // ---- phase B: out = Wout @ z + bout ----
    f32x4 accO[2][2];
    #pragma unroll
    for (int i = 0; i < 2; ++i) {
        int rb = mw * 32 + i * 16 + l4 * 4;
        f32x4 bo = *(const f32x4*)(bout + rb);
        #pragma unroll
        for (int ni = 0; ni < 2; ++ni) accO[i][ni] = bo;
    }
    #pragma unroll
    for (int s2 = 0; s2 < 2; ++s2) {
        short8 B[2];
        #pragma unroll
        for (int ni = 0; ni < 2; ++ni) {
            int col = nw * 32 + ni * 16 + l15;
            B[ni] = *(const short8*)(zs + col * 128 + ((s2 * 64 + l4 * 16) ^ SWZ(col)));
        }
        #pragma unroll
        for (int i = 0; i < 2; ++i) {
            short8 Ao = pW[4352 + (s2 * 4 + mw * 2 + i) * 64 + lane];
            #pragma unroll
            for (int ni = 0; ni < 2; ++ni)
                accO[i][ni] = __builtin_amdgcn_mfma_f32_16x16x32_bf16(Ao, B[ni], accO[i][ni], 0, 0, 0);
        }
    }
    #pragma unroll
    for (int i = 0; i < 2; ++i) {
        int rb = mw * 32 + i * 16 + l4 * 4;
        #pragma unroll
        for (int ni = 0; ni < 2; ++ni) {
            int col = nw * 32 + ni * 16 + l15;
            #pragma unroll
            for (int j = 0; j < 4; ++j)
                out[(size_t)(b * 64 + rb + j) * T_LEN + t0 + col] = accO[i][ni][j];
        }
    }
}

extern "C" void kernel_launch(void* const* d_in, const int* in_sizes, int n_in,
                              void* d_out, int out_size, void* d_ws, size_t ws_size,
                              hipStream_t stream) {
    const float* x     = (const float*)d_in[0];
    const float* cond  = (const float*)d_in[1];
    const float* wconv = (const float*)d_in[2];
    const float* bconv = (const float*)d_in[3];
    const float* wout  = (const float*)d_in[4];
    const float* bout  = (const float*)d_in[5];
    const float* wcond = (const float*)d_in[6];

    float* out  = (float*)d_out;
    float* skip = out + (size_t)8 * 64 * T_LEN;   // outputs concatenated in return order

    pack_weights<<<dim3(152), 256, 0, stream>>>(wconv, wcond, wout);
    wavenet_mfma<<<dim3(8 * (T_LEN / TT)), 256, 0, stream>>>(x, cond, bconv, bout, out, skip);
}

// Round 10
// 84.088 us; speedup vs baseline: 1.7711x; 1.7711x over previous
//
#include <hip/hip_runtime.h>

#define T_LEN 32768
#define TT 64
#define SWZ(row) ((((row) >> 1) & 7) << 4)

// LDS layout (bytes): xs 80*128, csA 64*128, csB 64*32
#define XS_OFF   0
#define CSA_OFF  10240
#define CSB_OFF  18432
#define LDS_SZ   20480   // 8 blocks/CU worth of LDS

typedef unsigned short ushort;
typedef unsigned int uint;
typedef __attribute__((ext_vector_type(8))) short short8;   // 8 bf16
typedef __attribute__((ext_vector_type(4))) float f32x4;
typedef __attribute__((ext_vector_type(2))) uint uint2v;

// Fragment-packed bf16 weights (one linear blob, L2-resident, read by all blocks).
// ushort layout: [0,32768) A1 full k-steps; [32768,34816) A8 half-frags; [34816,38912) A2.
__device__ __align__(16) ushort g_packAll[38912];

static __device__ __forceinline__ ushort f2bf(float f) {    // RNE f32->bf16
    uint u = __float_as_uint(f);
    u += 0x7fffu + ((u >> 16) & 1u);
    return (ushort)(u >> 16);
}

// A-frag (16x16x32): lane l holds A[16m + (l&15)][32s + (l>>4)*8 + j]
__global__ void pack_weights(const float* __restrict__ wconv,
                             const float* __restrict__ wcond,
                             const float* __restrict__ wout) {
    int idx = blockIdx.x * 256 + threadIdx.x;
    if (idx >= 38912) return;
    float v;
    if (idx < 32768) {                   // A1 full k-steps s=0..7 (conv 6 + cond 2)
        int j = idx & 7, lane = (idx >> 3) & 63, f = idx >> 9;  // f = s*8+g
        int s = f >> 3, g = f & 7;
        int row = (g & 3) * 16 + (lane & 15) + ((g & 4) ? 64 : 0);
        int k = s * 32 + (lane >> 4) * 8 + j;
        if (k < 192) v = wconv[row * 192 + (k & 63) * 3 + (k >> 6)];  // tap-major k
        else         v = wcond[row * 80 + (k - 192)];
    } else if (idx < 34816) {            // s=8 half-frags: k = cc 64..79 (l4<2 lanes)
        int e = idx - 32768;
        int j = e & 7, lane32 = (e >> 3) & 31, g = e >> 8;
        int row = (g & 3) * 16 + (lane32 & 15) + ((g & 4) ? 64 : 0);
        v = wcond[row * 80 + 64 + (lane32 >> 4) * 8 + j];
    } else {                             // A2: wout, f2 = s2*4 + m
        int e = idx - 34816;
        int j = e & 7, lane = (e >> 3) & 63, f2 = e >> 9;
        int row = (f2 & 3) * 16 + (lane & 15);
        v = wout[row * 64 + (f2 >> 2) * 32 + (lane >> 4) * 8 + j];
    }
    g_packAll[idx] = f2bf(v);
}

// 4096 blocks x 256 threads (4 waves), one 64-t tile each.
// NEW decomposition: wave wv owns ONE row-pair (rows wv*16..+16 and +64) over ALL
// 64 t (4 N-frags). Per s-step: 2 A-frag loads feed 8 MFMAs (was 4:8), with
// one-step A prefetch -> L2 latency covered by MFMA. launch_bounds(256,4):
// VGPR cap 128 (R9's (256,8) crushed to 32 VGPR and spilled; R4/R9 lesson).
__global__ __launch_bounds__(256, 4) void wavenet_mfma(
    const float* __restrict__ x, const float* __restrict__ cond,
    const float* __restrict__ bconv, const float* __restrict__ bout,
    float* __restrict__ out, float* __restrict__ skip)
{
    __shared__ __align__(16) char lds[LDS_SZ];
    const int tid = threadIdx.x;
    // XCD-aware swizzle: 512 consecutive t-tiles per XCD (bijective, 4096 % 8 == 0)
    const int bid = ((blockIdx.x & 7) << 9) | (blockIdx.x >> 3);
    const int b   = bid >> 9;
    const int t0  = (bid & 511) * TT;

    // ---- staging items: 0..159 x(oct,tq), 160..287 csA, 288..319 csB ----
    auto item_load = [&](int i, f32x4* v) {
        const float* p;
        bool ok = true;
        if (i < 160) {
            int oct = i & 7, tq = i >> 3;
            int g0 = t0 - 16 + tq * 4;
            ok = (g0 >= 0);
            p = x + (size_t)(b * 64 + oct * 8) * T_LEN + g0;
        } else if (i < 288) {
            int e = i - 160; int oct = e & 7, tq = e >> 3;
            p = cond + (size_t)(b * 80 + oct * 8) * T_LEN + t0 + tq * 4;
        } else {
            int e = i - 288; int octl = e & 1, tq = e >> 1;
            p = cond + (size_t)(b * 80 + 64 + octl * 8) * T_LEN + t0 + tq * 4;
        }
        if (ok) {
            #pragma unroll
            for (int j = 0; j < 8; ++j) v[j] = *(const f32x4*)(p + (size_t)j * T_LEN);
        } else {
            #pragma unroll
            for (int j = 0; j < 8; ++j) v[j] = (f32x4){0.f, 0.f, 0.f, 0.f};
        }
    };
    auto item_write = [&](int i, const f32x4* v) {
        char* basep; int tl, chunk; bool isB = false;
        if (i < 160)      { basep = lds + XS_OFF;  tl = (i >> 3) * 4;               chunk = (i & 7) * 16; }
        else if (i < 288) { int e = i - 160; basep = lds + CSA_OFF; tl = (e >> 3) * 4; chunk = (e & 7) * 16; }
        else              { int e = i - 288; basep = lds + CSB_OFF; tl = (e >> 1) * 4; chunk = (e & 1) * 16; isB = true; }
        #pragma unroll
        for (int r = 0; r < 4; ++r) {
            short8 pk;
            #pragma unroll
            for (int j = 0; j < 8; ++j) pk[j] = (short)f2bf(v[j][r]);
            int row = tl + r;
            int byte = isB ? row * 32 + (chunk ^ (((row >> 2) & 1) << 4))
                           : row * 128 + (chunk ^ SWZ(row));
            *(short8*)(basep + byte) = pk;
        }
    };

    // coverage: items [0,320), stride-256 loop
    for (int i = tid; i < 320; i += 256) {
        f32x4 va[8];
        item_load(i, va);
        item_write(i, va);
    }
    __syncthreads();

    const int lane = tid & 63, wv = tid >> 6;
    const int l4 = lane >> 4, l15 = lane & 15;
    const int rb = wv * 16 + l4 * 4;              // row base within each 64-row half
    const short8* pW = (const short8*)g_packAll;  // A1 at frag 0, A8 at 4096, A2 at 4352
    const short8 zero8 = (short8){0, 0, 0, 0, 0, 0, 0, 0};

    // ---- phase A: y = conv(*)x + Wcond*c + bconv ----
    f32x4 accA[4], accG[4];
    {
        f32x4 ba = *(const f32x4*)(bconv + rb);
        f32x4 bg = *(const f32x4*)(bconv + 64 + rb);
        #pragma unroll
        for (int ni = 0; ni < 4; ++ni) { accA[ni] = ba; accG[ni] = bg; }
    }

    short8 Aa = pW[(0 * 8 + wv) * 64 + lane];
    short8 Ag = pW[(0 * 8 + 4 + wv) * 64 + lane];
    #pragma unroll
    for (int s = 0; s < 9; ++s) {
        short8 Aan = zero8, Agn = zero8;
        if (s < 7) {                     // prefetch next full k-step
            Aan = pW[((s + 1) * 8 + wv) * 64 + lane];
            Agn = pW[((s + 1) * 8 + 4 + wv) * 64 + lane];
        } else if (s == 7) {             // prefetch s=8 half-frag (lanes l4<2 only)
            if (l4 < 2) {
                Aan = pW[4096 + wv * 32 + lane];
                Agn = pW[4096 + (4 + wv) * 32 + lane];
            }
        }
        short8 B[4];
        #pragma unroll
        for (int ni = 0; ni < 4; ++ni) {
            int col = ni * 16 + l15;
            if (s < 6) {            // conv tap s>>1, c-half s&1; tap shifts t by 8*tap
                int tl = col + (s >> 1) * 8;
                B[ni] = *(const short8*)(lds + XS_OFF + tl * 128 + (((s & 1) * 64 + l4 * 16) ^ SWZ(tl)));
            } else if (s < 8) {     // cond cc (s-6)*32..+32
                B[ni] = *(const short8*)(lds + CSA_OFF + col * 128 + (((s - 6) * 64 + l4 * 16) ^ SWZ(col)));
            } else {                // cond cc 64..79 (half-K; l4>=2 lanes have zero A)
                B[ni] = *(const short8*)(lds + CSB_OFF + col * 32 + (((l4 & 1) * 16) ^ (((col >> 2) & 1) << 4)));
            }
        }
        #pragma unroll
        for (int ni = 0; ni < 4; ++ni) {
            accA[ni] = __builtin_amdgcn_mfma_f32_16x16x32_bf16(Aa, B[ni], accA[ni], 0, 0, 0);
            accG[ni] = __builtin_amdgcn_mfma_f32_16x16x32_bf16(Ag, B[ni], accG[ni], 0, 0, 0);
        }
        Aa = Aan; Ag = Agn;
    }
    __syncthreads();   // xs/csA/csB reads done -> zs may overlay

    // ---- gate (register-only) + skip store + z -> LDS ----
    char* zs = lds + XS_OFF;    // [64 t][64 r] bf16, 128B rows, SWZ on t
    #pragma unroll
    for (int ni = 0; ni < 4; ++ni) {
        int col = ni * 16 + l15;
        float z[4];
        #pragma unroll
        for (int j = 0; j < 4; ++j) {
            float a = accA[ni][j], g = accG[ni][j];
            float th = 1.f - 2.f * __builtin_amdgcn_rcpf(__expf(2.f * a) + 1.f);
            float sg = __builtin_amdgcn_rcpf(1.f + __expf(-g));
            z[j] = th * sg;
            skip[(size_t)(b * 64 + rb + j) * T_LEN + t0 + col] = z[j];
        }
        uint p0 = (uint)f2bf(z[0]) | ((uint)f2bf(z[1]) << 16);
        uint p1 = (uint)f2bf(z[2]) | ((uint)f2bf(z[3]) << 16);
        *(uint2v*)(zs + col * 128 + ((uint)(rb * 2) ^ SWZ(col))) = (uint2v){p0, p1};
    }
    __syncthreads();

    // ---- phase B: out = Wout @ z + bout (wave wv: M-frag wv x 4 N-frags) ----
    f32x4 accO[4];
    {
        f32x4 bo = *(const f32x4*)(bout + rb);
        #pragma unroll
        for (int ni = 0; ni < 4; ++ni) accO[ni] = bo;
    }
    short8 Ao = pW[4352 + (0 * 4 + wv) * 64 + lane];
    #pragma unroll
    for (int s2 = 0; s2 < 2; ++s2) {
        short8 Aon = zero8;
        if (s2 == 0) Aon = pW[4352 + (1 * 4 + wv) * 64 + lane];
        short8 B[4];
        #pragma unroll
        for (int ni = 0; ni < 4; ++ni) {
            int col = ni * 16 + l15;
            B[ni] = *(const short8*)(zs + col * 128 + ((s2 * 64 + l4 * 16) ^ SWZ(col)));
        }
        #pragma unroll
        for (int ni = 0; ni < 4; ++ni)
            accO[ni] = __builtin_amdgcn_mfma_f32_16x16x32_bf16(Ao, B[ni], accO[ni], 0, 0, 0);
        Ao = Aon;
    }
    #pragma unroll
    for (int ni = 0; ni < 4; ++ni) {
        int col = ni * 16 + l15;
        #pragma unroll
        for (int j = 0; j < 4; ++j)
            out[(size_t)(b * 64 + rb + j) * T_LEN + t0 + col] = accO[ni][j];
    }
}

extern "C" void kernel_launch(void* const* d_in, const int* in_sizes, int n_in,
                              void* d_out, int out_size, void* d_ws, size_t ws_size,
                              hipStream_t stream) {
    const float* x     = (const float*)d_in[0];
    const float* cond  = (const float*)d_in[1];
    const float* wconv = (const float*)d_in[2];
    const float* bconv = (const float*)d_in[3];
    const float* wout  = (const float*)d_in[4];
    const float* bout  = (const float*)d_in[5];
    const float* wcond = (const float*)d_in[6];

    float* out  = (float*)d_out;
    float* skip = out + (size_t)8 * 64 * T_LEN;   // outputs concatenated in return order

    pack_weights<<<dim3(152), 256, 0, stream>>>(wconv, wcond, wout);
    wavenet_mfma<<<dim3(8 * (T_LEN / TT)), 256, 0, stream>>>(x, cond, bconv, bout, out, skip);
}